// Round 1
// baseline (6933.678 us; speedup 1.0000x reference)
//
#include <hip/hip_runtime.h>
#include <math.h>

#define BB 32
#define EE 512
#define VV 8192
#define TT 16
#define LL 4
#define FFD 2048
#define NHD 8
#define HDD 64
#define LDP 520   // padded LDS pitch (bf16 elems): 1040B rows -> 2-way-free b128 reads
#define SCALE_EMB 22.627416997969522f
#define GRID_MEGA 128

typedef __attribute__((ext_vector_type(8))) short bf16x8;   // 8 bf16 in 4 VGPRs
typedef __attribute__((ext_vector_type(4))) float f32x4;

__device__ __forceinline__ f32x4 mfma16(bf16x8 a, bf16x8 b, f32x4 c){
  return __builtin_amdgcn_mfma_f32_16x16x32_bf16(a, b, c, 0, 0, 0);
}

// ---------------- helpers ----------------
__device__ __forceinline__ float wave_sum(float v){
  for (int o = 32; o; o >>= 1) v += __shfl_down(v, o);
  return __shfl(v, 0);
}
__device__ __forceinline__ float wave_max(float v){
  for (int o = 32; o; o >>= 1) v = fmaxf(v, __shfl_down(v, o));
  return __shfl(v, 0);
}
__device__ __forceinline__ unsigned short f_to_bf(float f){
  unsigned u = __float_as_uint(f);
  unsigned r = (u + 0x7fffu + ((u >> 16) & 1u)) >> 16;
  return (unsigned short)r;
}
__device__ __forceinline__ float2 bf2_to_f2(const unsigned short* p){
  unsigned u = *(const unsigned*)p;
  float2 r;
  r.x = __uint_as_float(u << 16);
  r.y = __uint_as_float(u & 0xffff0000u);
  return r;
}

// device-scope grid barrier: monotonic counter in workspace (reset by k_init each launch).
// Leader: release fence -> arrive -> spin (agent-scope) -> acquire fence.
__device__ __forceinline__ void gsync(unsigned* bar, unsigned& gen){
  gen++;
  __syncthreads();
  if (threadIdx.x == 0){
    __threadfence();
    __hip_atomic_fetch_add(bar, 1u, __ATOMIC_RELAXED, __HIP_MEMORY_SCOPE_AGENT);
    const unsigned tgt = gen * (unsigned)gridDim.x;
    while (__hip_atomic_load(bar, __ATOMIC_RELAXED, __HIP_MEMORY_SCOPE_AGENT) < tgt)
      __builtin_amdgcn_s_sleep(1);
    __threadfence();
  }
  __syncthreads();
}

// fp32 VALU GEMM core (kept for the one-off prologue kernels k_penc/k_pca)
__device__ __forceinline__ void gemm_chunk(const float* __restrict__ wrow0, int ldw,
    const unsigned short* xs, float* wt, float acc[4][2]){
  const int t = threadIdx.x, fg = t & 15, bg = t >> 4;
  #pragma unroll 1
  for (int c = 0; c < 8; ++c){
    const int k0 = c*64;
    __syncthreads();
    {
      int i = t*4;
      #pragma unroll
      for (int p = 0; p < 4; ++p, i += 1024){
        const int fr = i >> 6, kk = i & 63;
        float4 v = *(const float4*)(wrow0 + (size_t)fr*ldw + k0 + kk);
        wt[(kk+0)*68 + fr] = v.x;
        wt[(kk+1)*68 + fr] = v.y;
        wt[(kk+2)*68 + fr] = v.z;
        wt[(kk+3)*68 + fr] = v.w;
      }
    }
    __syncthreads();
    const unsigned short* xr0 = xs + (bg*2)*EE + k0;
    const unsigned short* xr1 = xr0 + EE;
    #pragma unroll 8
    for (int k = 0; k < 64; k += 2){
      float w0[4], w1[4];
      *(float4*)w0 = *(const float4*)(wt + (k+0)*68 + fg*4);
      *(float4*)w1 = *(const float4*)(wt + (k+1)*68 + fg*4);
      float2 xv0 = bf2_to_f2(xr0 + k);
      float2 xv1 = bf2_to_f2(xr1 + k);
      #pragma unroll
      for (int i = 0; i < 4; ++i){
        acc[i][0] += w0[i]*xv0.x + w1[i]*xv0.y;
        acc[i][1] += w0[i]*xv1.x + w1[i]*xv1.y;
      }
    }
  }
}

// Stage [B,E] activations into padded-LDS bf16, optional pending LN3 from ybuf.
// If xlnout != null also materialize the LN'd fp32 rows.
__device__ __forceinline__ void stage_x_p(unsigned short* xs,
    const float* __restrict__ xraw, const float* __restrict__ ybuf,
    const float* __restrict__ g, const float* __restrict__ bt, int use_ln,
    float* __restrict__ xlnout){
  if (!use_ln){
    for (int i = threadIdx.x; i < BB*EE; i += 256){
      int r = i >> 9, c = i & 511;
      xs[r*LDP + c] = f_to_bf(xraw[i]);
    }
  } else {
    const int lane = threadIdx.x & 63, wv = threadIdx.x >> 6;
    for (int r = wv*8; r < wv*8 + 8; ++r){
      float vals[8]; float s = 0.f, s2 = 0.f;
      #pragma unroll
      for (int j = 0; j < 8; ++j){
        float v = ybuf[r*EE + lane + j*64];
        vals[j] = v; s += v; s2 += v*v;
      }
      s = wave_sum(s); s2 = wave_sum(s2);
      float m = s * (1.f/EE);
      float inv = rsqrtf(s2*(1.f/EE) - m*m + 1e-5f);
      #pragma unroll
      for (int j = 0; j < 8; ++j){
        int c = lane + j*64;
        float v = (vals[j]-m)*inv*g[c] + bt[c];
        xs[r*LDP + c] = f_to_bf(v);
        if (xlnout) xlnout[r*EE + c] = v;
      }
    }
  }
  __syncthreads();
}

// ---------------- prologue kernels ----------------

__global__ __launch_bounds__(256) void k_init(const float* __restrict__ special,
    float* __restrict__ dseq, float* __restrict__ x, unsigned* __restrict__ bar){
  if (blockIdx.x == 0 && threadIdx.x == 0) *bar = 0u;
  int idx = blockIdx.x*256 + threadIdx.x;
  if (idx < BB*VV){
    int b = idx >> 13, v = idx & (VV-1);
    dseq[(size_t)b*((TT+1)*VV) + (size_t)TT*VV + v] = (v == 0) ? 1.f : 0.f;
  } else {
    int i = idx - BB*VV;
    x[i] = special[i & (EE-1)];
  }
}

__global__ __launch_bounds__(256) void k_penc(const float* __restrict__ enc,
    const float* __restrict__ w, const float* __restrict__ bias, float* __restrict__ venc){
  __shared__ unsigned short xs[BB*EE];
  __shared__ float wt[64*68];
  const int l = blockIdx.x >> 3, et = blockIdx.x & 7;
  for (int i = threadIdx.x; i < BB*EE; i += 256) xs[i] = f_to_bf(enc[i]);
  const int t = threadIdx.x, fg = t & 15, bg = t >> 4;
  const int f0 = et*64;
  const float* wl = w + (size_t)l*3*EE*EE + (size_t)(2*EE + f0)*EE;
  const float* bl = bias + l*3*EE + 2*EE + f0;
  float acc[4][2];
  #pragma unroll
  for (int i = 0; i < 4; ++i){ float bv = bl[fg*4+i]; acc[i][0] = bv; acc[i][1] = bv; }
  gemm_chunk(wl, EE, xs, wt, acc);
  #pragma unroll
  for (int i = 0; i < 4; ++i)
    #pragma unroll
    for (int j = 0; j < 2; ++j)
      venc[(size_t)l*BB*EE + (bg*2+j)*EE + f0 + fg*4 + i] = acc[i][j];
}

__global__ __launch_bounds__(256) void k_pca(const float* __restrict__ venc,
    const float* __restrict__ w, const float* __restrict__ bias, float* __restrict__ cac){
  __shared__ unsigned short xs[BB*EE];
  __shared__ float wt[64*68];
  const int l = blockIdx.x >> 3, et = blockIdx.x & 7;
  const float* vin = venc + (size_t)l*BB*EE;
  for (int i = threadIdx.x; i < BB*EE; i += 256) xs[i] = f_to_bf(vin[i]);
  const int t = threadIdx.x, fg = t & 15, bg = t >> 4;
  const int f0 = et*64;
  const float* wl = w + (size_t)l*EE*EE + (size_t)f0*EE;
  const float* bl = bias + l*EE + f0;
  float acc[4][2];
  #pragma unroll
  for (int i = 0; i < 4; ++i){ float bv = bl[fg*4+i]; acc[i][0] = bv; acc[i][1] = bv; }
  gemm_chunk(wl, EE, xs, wt, acc);
  #pragma unroll
  for (int i = 0; i < 4; ++i)
    #pragma unroll
    for (int j = 0; j < 2; ++j)
      cac[(size_t)l*BB*EE + (bg*2+j)*EE + f0 + fg*4 + i] = acc[i][j];
}

__global__ __launch_bounds__(256) void k_cvt(const float* __restrict__ s,
    unsigned short* __restrict__ d, int n4){
  int i = blockIdx.x*256 + threadIdx.x;
  if (i < n4){
    float4 v = ((const float4*)s)[i];
    ushort4 o;
    o.x = f_to_bf(v.x); o.y = f_to_bf(v.y); o.z = f_to_bf(v.z); o.w = f_to_bf(v.w);
    ((ushort4*)d)[i] = o;
  }
}

__global__ __launch_bounds__(256) void k_embT(const float* __restrict__ emb,
    unsigned short* __restrict__ eT){
  __shared__ unsigned short tl[64][68];
  const int vt = blockIdx.x >> 3, et = blockIdx.x & 7;
  const int v0 = vt*64, e0 = et*64;
  for (int i = threadIdx.x; i < 64*64; i += 256){
    int vv = i >> 6, ee = i & 63;
    tl[vv][ee] = f_to_bf(emb[(size_t)(v0+vv)*EE + e0 + ee]);
  }
  __syncthreads();
  for (int i = threadIdx.x; i < 64*64; i += 256){
    int ee = i >> 6, vv = i & 63;
    eT[(size_t)(e0+ee)*VV + v0 + vv] = tl[vv][ee];
  }
}

// ---------------- mega-kernel phases (device functions) ----------------

// qkv (head-chunked) + attention for head h. Block h computes q/k/v chunks of
// head h for all 32 rows (3x 64-feat MFMA passes), then scores/softmax/PV.
__device__ void ph_qkv_attn(int h, unsigned short* xs, float* qs, float* att,
    const float* __restrict__ x, const float* __restrict__ ybuf,
    const float* __restrict__ lg, const float* __restrict__ lb, int use_ln,
    const unsigned short* __restrict__ Wb, const float* __restrict__ bias,
    float* __restrict__ kcl, float* __restrict__ vcl, float* __restrict__ xln,
    unsigned short* __restrict__ obf, int tpos, int tlen){
  stage_x_p(xs, x, ybuf, lg, lb, use_ln, (use_ln && h == 0) ? xln : nullptr);
  const int t = threadIdx.x, w = t >> 6, lane = t & 63;
  const int lm = lane & 15, kg = lane >> 4;
  const unsigned short* b0r = xs + lm*LDP + kg*8;
  const unsigned short* b1r = xs + (lm+16)*LDP + kg*8;
  #pragma unroll
  for (int c = 0; c < 3; ++c){
    const int fbase = c*EE + h*64 + w*16;
    const unsigned short* ar = Wb + (size_t)(fbase + lm)*EE + kg*8;
    f32x4 acc0 = {0.f,0.f,0.f,0.f}, acc1 = {0.f,0.f,0.f,0.f};
    #pragma unroll 4
    for (int ks = 0; ks < 16; ++ks){
      bf16x8 a  = *reinterpret_cast<const bf16x8*>(ar + ks*32);
      bf16x8 b0 = *reinterpret_cast<const bf16x8*>(b0r + ks*32);
      bf16x8 b1 = *reinterpret_cast<const bf16x8*>(b1r + ks*32);
      acc0 = mfma16(a, b0, acc0);
      acc1 = mfma16(a, b1, acc1);
    }
    #pragma unroll
    for (int r = 0; r < 4; ++r){
      const int frel = w*16 + kg*4 + r;                 // 0..63 within chunk
      const float bv = bias[c*EE + h*64 + frel];
      float v0 = acc0[r] + bv, v1 = acc1[r] + bv;
      if (c == 0){
        qs[lm*68 + frel] = v0;
        qs[(lm+16)*68 + frel] = v1;
      } else if (c == 1){
        kcl[((lm*NHD + h)*TT + tpos)*HDD + frel] = v0;
        kcl[(((lm+16)*NHD + h)*TT + tpos)*HDD + frel] = v1;
      } else {
        vcl[((lm*NHD + h)*TT + tpos)*HDD + frel] = v0;
        vcl[(((lm+16)*NHD + h)*TT + tpos)*HDD + frel] = v1;
      }
    }
  }
  __syncthreads();
  // scores: 2 (b,j) pairs per thread
  #pragma unroll
  for (int pp = 0; pp < 2; ++pp){
    const int p = t + pp*256;
    const int b = p >> 4, j = p & 15;
    if (j < tlen){
      const float* qrow = qs + b*68;
      const float* krow = kcl + ((b*NHD + h)*TT + j)*HDD;
      float a = 0.f;
      #pragma unroll
      for (int d = 0; d < HDD; d += 4){
        float4 qv = *(const float4*)(qrow + d);
        float4 kv = *(const float4*)(krow + d);
        a += qv.x*kv.x + qv.y*kv.y + qv.z*kv.z + qv.w*kv.w;
      }
      att[b*16 + j] = a*0.125f;
    }
  }
  __syncthreads();
  if (t < 32){
    const int b = t;
    float m = -1e30f;
    for (int j = 0; j < tlen; ++j) m = fmaxf(m, att[b*16 + j]);
    float s = 0.f;
    for (int j = 0; j < tlen; ++j) s += __expf(att[b*16 + j] - m);
    float inv = 1.f/s;
    for (int j = 0; j < tlen; ++j) att[b*16 + j] = __expf(att[b*16 + j] - m)*inv;
  }
  __syncthreads();
  // PV: thread -> (b, 8 d-values)
  {
    const int b = t >> 3, d0 = (t & 7)*8;
    float acc[8];
    #pragma unroll
    for (int i = 0; i < 8; ++i) acc[i] = 0.f;
    const float* vrow = vcl + ((b*NHD + h)*TT)*HDD + d0;
    for (int j = 0; j < tlen; ++j){
      const float a = att[b*16 + j];
      float4 v0 = *(const float4*)(vrow + j*HDD);
      float4 v1 = *(const float4*)(vrow + j*HDD + 4);
      acc[0] += a*v0.x; acc[1] += a*v0.y; acc[2] += a*v0.z; acc[3] += a*v0.w;
      acc[4] += a*v1.x; acc[5] += a*v1.y; acc[6] += a*v1.z; acc[7] += a*v1.w;
    }
    #pragma unroll
    for (int i = 0; i < 8; ++i) obf[b*EE + h*HDD + d0 + i] = f_to_bf(acc[i]);
  }
}

__device__ void ph_outp(int blk, const unsigned short* __restrict__ obf,
    const unsigned short* __restrict__ Wb, const float* __restrict__ ob,
    const float* __restrict__ resid, float* __restrict__ o2){
  const int t = threadIdx.x, w = t >> 6, l = t & 63;
  const int lm = l & 15, kg = l >> 4;
  const int f0w = blk*64 + w*16;
  const unsigned short* ar = Wb + (size_t)(f0w + lm)*EE + kg*8;
  const unsigned short* b0r = obf + lm*EE + kg*8;
  const unsigned short* b1r = obf + (lm+16)*EE + kg*8;
  f32x4 acc0 = {0.f,0.f,0.f,0.f}, acc1 = {0.f,0.f,0.f,0.f};
  #pragma unroll 4
  for (int ks = 0; ks < 16; ++ks){
    bf16x8 a  = *reinterpret_cast<const bf16x8*>(ar + ks*32);
    bf16x8 b0 = *reinterpret_cast<const bf16x8*>(b0r + ks*32);
    bf16x8 b1 = *reinterpret_cast<const bf16x8*>(b1r + ks*32);
    acc0 = mfma16(a, b0, acc0);
    acc1 = mfma16(a, b1, acc1);
  }
  #pragma unroll
  for (int r = 0; r < 4; ++r){
    const int f = f0w + kg*4 + r;
    const float bv = ob[f];
    o2[lm*EE + f]      = acc0[r] + bv + resid[lm*EE + f];
    o2[(lm+16)*EE + f] = acc1[r] + bv + resid[(lm+16)*EE + f];
  }
}

__device__ void ph_ffn1(int blk, unsigned short* xs,
    const float* __restrict__ o2, const float* __restrict__ cac,
    const float* __restrict__ g1, const float* __restrict__ b1g,
    const float* __restrict__ g2, const float* __restrict__ b2g,
    const float* __restrict__ b2bias,
    const unsigned short* __restrict__ Wb, const float* __restrict__ bias,
    unsigned short* __restrict__ Hb, float* __restrict__ ybuf){
  {
    float* yi = (blk == 0) ? ybuf : nullptr;
    const int lane = threadIdx.x & 63, wv = threadIdx.x >> 6;
    for (int r = wv*8; r < wv*8 + 8; ++r){
      float vals[8]; float s = 0.f, s2 = 0.f;
      #pragma unroll
      for (int j = 0; j < 8; ++j){
        float v = o2[r*EE + lane + j*64];
        vals[j] = v; s += v; s2 += v*v;
      }
      s = wave_sum(s); s2 = wave_sum(s2);
      float m = s*(1.f/EE), inv = rsqrtf(s2*(1.f/EE) - m*m + 1e-5f);
      float nv[8]; float u = 0.f, u2 = 0.f;
      #pragma unroll
      for (int j = 0; j < 8; ++j){
        int c = lane + j*64;
        float v = (vals[j]-m)*inv*g1[c] + b1g[c] + cac[r*EE + c];
        nv[j] = v; u += v; u2 += v*v;
      }
      u = wave_sum(u); u2 = wave_sum(u2);
      float m2 = u*(1.f/EE), inv2 = rsqrtf(u2*(1.f/EE) - m2*m2 + 1e-5f);
      #pragma unroll
      for (int j = 0; j < 8; ++j){
        int c = lane + j*64;
        float v = (nv[j]-m2)*inv2*g2[c] + b2g[c];
        xs[r*LDP + c] = f_to_bf(v);
        if (yi) yi[r*EE + c] = v + b2bias[c];
      }
    }
    __syncthreads();
  }
  const int t = threadIdx.x, w = t >> 6, l = t & 63;
  const int lm = l & 15, kg = l >> 4;
  const int f0w = blk*64 + w*16;
  const unsigned short* ar = Wb + (size_t)(f0w + lm)*EE + kg*8;
  const unsigned short* b0r = xs + lm*LDP + kg*8;
  const unsigned short* b1r = xs + (lm+16)*LDP + kg*8;
  f32x4 acc0 = {0.f,0.f,0.f,0.f}, acc1 = {0.f,0.f,0.f,0.f};
  #pragma unroll 4
  for (int ks = 0; ks < 16; ++ks){
    bf16x8 a  = *reinterpret_cast<const bf16x8*>(ar + ks*32);
    bf16x8 b0 = *reinterpret_cast<const bf16x8*>(b0r + ks*32);
    bf16x8 b1 = *reinterpret_cast<const bf16x8*>(b1r + ks*32);
    acc0 = mfma16(a, b0, acc0);
    acc1 = mfma16(a, b1, acc1);
  }
  #pragma unroll
  for (int r = 0; r < 4; ++r){
    const int f = f0w + kg*4 + r;
    const float bv = bias[f];
    float v0 = acc0[r] + bv, v1 = acc1[r] + bv;
    v0 = 0.5f*v0*(1.f + erff(v0*0.70710678118654752f));
    v1 = 0.5f*v1*(1.f + erff(v1*0.70710678118654752f));
    Hb[lm*FFD + f] = f_to_bf(v0);
    Hb[(lm+16)*FFD + f] = f_to_bf(v1);
  }
}

__device__ void ph_ffn2(int blk, const unsigned short* __restrict__ Hb,
    const unsigned short* __restrict__ Wb, float* __restrict__ ybuf){
  const int t = threadIdx.x, w = t >> 6, l = t & 63;
  const int lm = l & 15, kg = l >> 4;
  const int f0w = (blk & 7)*64 + w*16;
  const int k0 = (blk >> 3)*512;
  const unsigned short* ar = Wb + (size_t)(f0w + lm)*FFD + k0 + kg*8;
  const unsigned short* b0r = Hb + lm*FFD + k0 + kg*8;
  const unsigned short* b1r = Hb + (lm+16)*FFD + k0 + kg*8;
  f32x4 acc0 = {0.f,0.f,0.f,0.f}, acc1 = {0.f,0.f,0.f,0.f};
  #pragma unroll 4
  for (int ks = 0; ks < 16; ++ks){
    bf16x8 a  = *reinterpret_cast<const bf16x8*>(ar + ks*32);
    bf16x8 b0 = *reinterpret_cast<const bf16x8*>(b0r + ks*32);
    bf16x8 b1 = *reinterpret_cast<const bf16x8*>(b1r + ks*32);
    acc0 = mfma16(a, b0, acc0);
    acc1 = mfma16(a, b1, acc1);
  }
  #pragma unroll
  for (int r = 0; r < 4; ++r){
    const int f = f0w + kg*4 + r;
    atomicAdd(&ybuf[lm*EE + f], acc0[r]);
    atomicAdd(&ybuf[(lm+16)*EE + f], acc1[r]);
  }
}

__device__ void ph_logits(int blk, unsigned short* xs,
    const float* __restrict__ ybuf, const float* __restrict__ lng, const float* __restrict__ lnb,
    const unsigned short* __restrict__ Wb, const float* __restrict__ bias,
    float* __restrict__ logits){
  stage_x_p(xs, nullptr, ybuf, lng, lnb, 1, nullptr);
  const int t = threadIdx.x, w = t >> 6, l = t & 63;
  const int lm = l & 15, kg = l >> 4;
  const int f0w = blk*64 + w*16;
  const unsigned short* ar = Wb + (size_t)(f0w + lm)*EE + kg*8;
  const unsigned short* b0r = xs + lm*LDP + kg*8;
  const unsigned short* b1r = xs + (lm+16)*LDP + kg*8;
  f32x4 acc0 = {0.f,0.f,0.f,0.f}, acc1 = {0.f,0.f,0.f,0.f};
  #pragma unroll 4
  for (int ks = 0; ks < 16; ++ks){
    bf16x8 a  = *reinterpret_cast<const bf16x8*>(ar + ks*32);
    bf16x8 b0 = *reinterpret_cast<const bf16x8*>(b0r + ks*32);
    bf16x8 b1 = *reinterpret_cast<const bf16x8*>(b1r + ks*32);
    acc0 = mfma16(a, b0, acc0);
    acc1 = mfma16(a, b1, acc1);
  }
  #pragma unroll
  for (int r = 0; r < 4; ++r){
    const int f = f0w + kg*4 + r;
    const float bv = bias[f];
    logits[lm*VV + f]      = acc0[r] + bv;
    logits[(lm+16)*VV + f] = acc1[r] + bv;
  }
}

__device__ void ph_softmax(int b, float* red, const float* __restrict__ logits,
    const float* __restrict__ gum, float* __restrict__ dseq, float* __restrict__ ddist,
    unsigned short* __restrict__ sbf, float* __restrict__ x, int step){
  const int t = threadIdx.x, lane = t & 63, wv = t >> 6;
  const float* lr = logits + (size_t)b*VV;
  const float* gr = gum + (size_t)b*VV;
  float m1 = -1e30f, m2 = -1e30f;
  for (int i = t; i < VV; i += 256){
    float l = lr[i];
    m1 = fmaxf(m1, l);
    m2 = fmaxf(m2, l + gr[i]);
  }
  for (int o = 32; o; o >>= 1){ m1 = fmaxf(m1, __shfl_down(m1,o)); m2 = fmaxf(m2, __shfl_down(m2,o)); }
  if (lane == 0){ red[wv] = m1; red[4+wv] = m2; }
  __syncthreads();
  m1 = fmaxf(fmaxf(red[0],red[1]), fmaxf(red[2],red[3]));
  m2 = fmaxf(fmaxf(red[4],red[5]), fmaxf(red[6],red[7]));
  __syncthreads();
  float s1 = 0.f, s2 = 0.f;
  for (int i = t; i < VV; i += 256){
    float l = lr[i];
    s1 += __expf(l - m1);
    s2 += __expf(l + gr[i] - m2);
  }
  for (int o = 32; o; o >>= 1){ s1 += __shfl_down(s1,o); s2 += __shfl_down(s2,o); }
  if (lane == 0){ red[wv] = s1; red[4+wv] = s2; }
  __syncthreads();
  s1 = red[0]+red[1]+red[2]+red[3];
  s2 = red[4]+red[5]+red[6]+red[7];
  float r1 = 1.f/s1, r2 = 1.f/s2;
  float* dq = dseq + (size_t)b*((TT+1)*VV) + (size_t)step*VV;
  float* dd = ddist + (size_t)b*VV;
  for (int i = t; i < VV; i += 256){
    float l = lr[i];
    dd[i] = __expf(l - m1)*r1;
    float qv = __expf(l + gr[i] - m2)*r2;
    dq[i] = qv;
    sbf[(size_t)b*VV + i] = f_to_bf(qv);
  }
  for (int i = t; i < EE; i += 256) x[b*EE + i] = 0.f;
}

__device__ void ph_embed(int blk, const unsigned short* __restrict__ eT,
    const unsigned short* __restrict__ sbf, float* __restrict__ x){
  const int t = threadIdx.x, w = t >> 6, l = t & 63;
  const int lm = l & 15, kg = l >> 4;
  const int e0w = (blk & 7)*64 + w*16;
  const int v0 = (blk >> 3)*1024;
  const unsigned short* ar  = eT + (size_t)(e0w + lm)*VV + v0 + kg*8;
  const unsigned short* b0r = sbf + (size_t)lm*VV + v0 + kg*8;
  const unsigned short* b1r = sbf + (size_t)(lm+16)*VV + v0 + kg*8;
  f32x4 acc0 = {0.f,0.f,0.f,0.f}, acc1 = {0.f,0.f,0.f,0.f};
  #pragma unroll 8
  for (int ks = 0; ks < 32; ++ks){
    bf16x8 a  = *reinterpret_cast<const bf16x8*>(ar + ks*32);
    bf16x8 b0 = *reinterpret_cast<const bf16x8*>(b0r + ks*32);
    bf16x8 b1 = *reinterpret_cast<const bf16x8*>(b1r + ks*32);
    acc0 = mfma16(a, b0, acc0);
    acc1 = mfma16(a, b1, acc1);
  }
  #pragma unroll
  for (int r = 0; r < 4; ++r){
    const int e = e0w + kg*4 + r;
    atomicAdd(&x[lm*EE + e], acc0[r]*SCALE_EMB);
    atomicAdd(&x[(lm+16)*EE + e], acc1[r]*SCALE_EMB);
  }
}

// ---------------- the megakernel ----------------

struct MegaParams {
  float* x; float* y; float* xln; float* o2; float* logits;
  const float* cac;
  float* kcache; float* vcache;
  unsigned short* obf; unsigned short* Hb; unsigned short* sbf;
  const unsigned short* wqkvb; const unsigned short* owb;
  const unsigned short* w1b; const unsigned short* w2b;
  const unsigned short* outwb; const unsigned short* eTb;
  const float* saqb; const float* saob;
  const float* l1g; const float* l1b; const float* l2g; const float* l2b;
  const float* l3g; const float* l3b;
  const float* b1; const float* b2; const float* outb; const float* gumb;
  float* dseq; float* ddist;
  unsigned* bar;
};

__global__ __launch_bounds__(256) void k_mega(MegaParams P){
  __shared__ __align__(16) unsigned char SMEM[44032];
  unsigned short* xs = (unsigned short*)SMEM;          // 33280 B  (BB*LDP bf16)
  float* qs  = (float*)(SMEM + 33280);                 //  8704 B  (32x68 f32)
  float* att = (float*)(SMEM + 41984);                 //  2048 B  (32x16 f32)
  const int blk = blockIdx.x;
  unsigned gen = 0;

  for (int step = 0; step < TT; ++step){
    const int tpos = step, tlen = step + 1;
    for (int l = 0; l < LL; ++l){
      const int use_ln = (l > 0);
      const float* lg = P.l3g + (use_ln ? (l-1)*EE : 0);
      const float* lb = P.l3b + (use_ln ? (l-1)*EE : 0);
      float* kcl = P.kcache + (size_t)l*BB*EE*TT;
      float* vcl = P.vcache + (size_t)l*BB*EE*TT;
      if (blk < NHD)
        ph_qkv_attn(blk, xs, qs, att, P.x, P.y, lg, lb, use_ln,
            P.wqkvb + (size_t)l*3*EE*EE, P.saqb + (size_t)l*3*EE,
            kcl, vcl, P.xln, P.obf, tpos, tlen);
      gsync(P.bar, gen);
      if (blk < 8)
        ph_outp(blk, P.obf, P.owb + (size_t)l*EE*EE, P.saob + (size_t)l*EE,
            use_ln ? P.xln : P.x, P.o2);
      gsync(P.bar, gen);
      if (blk < 32)
        ph_ffn1(blk, xs, P.o2, P.cac + (size_t)l*BB*EE,
            P.l1g + l*EE, P.l1b + l*EE, P.l2g + l*EE, P.l2b + l*EE, P.b2 + l*EE,
            P.w1b + (size_t)l*FFD*EE, P.b1 + l*FFD, P.Hb, P.y);
      gsync(P.bar, gen);
      if (blk < 32)
        ph_ffn2(blk, P.Hb, P.w2b + (size_t)l*EE*FFD, P.y);
      gsync(P.bar, gen);
    }
    ph_logits(blk, xs, P.y, P.l3g + 3*EE, P.l3b + 3*EE, P.outwb, P.outb, P.logits);
    gsync(P.bar, gen);
    if (blk < 32)
      ph_softmax(blk, (float*)SMEM, P.logits, P.gumb + (size_t)step*BB*VV,
          P.dseq, P.ddist + (size_t)step*BB*VV, P.sbf, P.x, step);
    gsync(P.bar, gen);
    if (blk < 64)
      ph_embed(blk, P.eTb, P.sbf, P.x);
    gsync(P.bar, gen);
  }
}

// ---------------- host ----------------
extern "C" void kernel_launch(void* const* d_in, const int* in_sizes, int n_in,
                              void* d_out, int out_size, void* d_ws, size_t ws_size,
                              hipStream_t stream){
  (void)in_sizes; (void)n_in; (void)out_size; (void)ws_size;
  const float* enc  = (const float*)d_in[0];
  const float* spec = (const float*)d_in[1];
  const float* embw = (const float*)d_in[2];
  const float* outw = (const float*)d_in[3];
  const float* outb = (const float*)d_in[4];
  const float* gumb = (const float*)d_in[5];
  const float* saqw = (const float*)d_in[6];
  const float* saqb = (const float*)d_in[7];
  const float* saow = (const float*)d_in[8];
  const float* saob = (const float*)d_in[9];
  const float* caqw = (const float*)d_in[10];
  const float* caqb = (const float*)d_in[11];
  const float* caow = (const float*)d_in[12];
  const float* caob = (const float*)d_in[13];
  const float* l1g  = (const float*)d_in[14];
  const float* l1b  = (const float*)d_in[15];
  const float* l2g  = (const float*)d_in[16];
  const float* l2b  = (const float*)d_in[17];
  const float* l3g  = (const float*)d_in[18];
  const float* l3b  = (const float*)d_in[19];
  const float* w1   = (const float*)d_in[20];
  const float* b1   = (const float*)d_in[21];
  const float* w2   = (const float*)d_in[22];
  const float* b2   = (const float*)d_in[23];

  float* dout = (float*)d_out;
  float* dseq = dout;
  float* ddistbase = dout + (size_t)BB*(TT+1)*VV;

  unsigned char* p = (unsigned char*)d_ws;
  auto alloc = [&](size_t bytes) -> void* {
    void* r = (void*)p; p += (bytes + 255) & ~(size_t)255; return r;
  };
  float* x      = (float*)alloc(BB*EE*4);
  float* y      = (float*)alloc(BB*EE*4);
  float* xln    = (float*)alloc(BB*EE*4);
  float* o2     = (float*)alloc(BB*EE*4);
  float* logits = (float*)alloc((size_t)BB*VV*4);
  float* venc   = (float*)alloc((size_t)LL*BB*EE*4);
  float* cac    = (float*)alloc((size_t)LL*BB*EE*4);
  float* kcache = (float*)alloc((size_t)LL*BB*EE*TT*4);
  float* vcache = (float*)alloc((size_t)LL*BB*EE*TT*4);
  unsigned short* obf   = (unsigned short*)alloc(BB*EE*2);
  unsigned short* Hb    = (unsigned short*)alloc(BB*FFD*2);
  unsigned short* sbf   = (unsigned short*)alloc((size_t)BB*VV*2);
  unsigned short* wqkvb = (unsigned short*)alloc((size_t)LL*3*EE*EE*2);
  unsigned short* owb   = (unsigned short*)alloc((size_t)LL*EE*EE*2);
  unsigned short* w1b   = (unsigned short*)alloc((size_t)LL*FFD*EE*2);
  unsigned short* w2b   = (unsigned short*)alloc((size_t)LL*FFD*EE*2);
  unsigned short* outwb = (unsigned short*)alloc((size_t)VV*EE*2);
  unsigned short* eTb   = (unsigned short*)alloc((size_t)EE*VV*2);
  unsigned* bar = (unsigned*)alloc(256);

  // prologue: init (+barrier reset), cross-attn constants, bf16 weight conversions
  k_init<<<1088, 256, 0, stream>>>(spec, dseq, x, bar);
  k_penc<<<32, 256, 0, stream>>>(enc, caqw, caqb, venc);
  k_pca<<<32, 256, 0, stream>>>(venc, caow, caob, cac);
  k_cvt<<<(LL*3*EE*EE/4 + 255)/256, 256, 0, stream>>>(saqw, wqkvb, LL*3*EE*EE/4);
  k_cvt<<<(LL*EE*EE/4 + 255)/256, 256, 0, stream>>>(saow, owb, LL*EE*EE/4);
  k_cvt<<<(LL*FFD*EE/4 + 255)/256, 256, 0, stream>>>(w1, w1b, LL*FFD*EE/4);
  k_cvt<<<(LL*FFD*EE/4 + 255)/256, 256, 0, stream>>>(w2, w2b, LL*FFD*EE/4);
  k_cvt<<<(VV*EE/4 + 255)/256, 256, 0, stream>>>(outw, outwb, VV*EE/4);
  k_embT<<<1024, 256, 0, stream>>>(embw, eTb);

  MegaParams mp;
  mp.x = x; mp.y = y; mp.xln = xln; mp.o2 = o2; mp.logits = logits;
  mp.cac = cac; mp.kcache = kcache; mp.vcache = vcache;
  mp.obf = obf; mp.Hb = Hb; mp.sbf = sbf;
  mp.wqkvb = wqkvb; mp.owb = owb; mp.w1b = w1b; mp.w2b = w2b;
  mp.outwb = outwb; mp.eTb = eTb;
  mp.saqb = saqb; mp.saob = saob;
  mp.l1g = l1g; mp.l1b = l1b; mp.l2g = l2g; mp.l2b = l2b;
  mp.l3g = l3g; mp.l3b = l3b;
  mp.b1 = b1; mp.b2 = b2; mp.outb = outb; mp.gumb = gumb;
  mp.dseq = dseq; mp.ddist = ddistbase;
  mp.bar = bar;

  // 128 blocks x 256 threads: <=1 block/CU strictly needed resources (44KB LDS,
  // 4 waves) on 256 CUs -> all blocks co-resident; grid barriers are safe.
  k_mega<<<GRID_MEGA, 256, 0, stream>>>(mp);
}

// Round 2
// 5233.486 us; speedup vs baseline: 1.3249x; 1.3249x over previous
//
#include <hip/hip_runtime.h>
#include <math.h>

#define BB 32
#define EE 512
#define VV 8192
#define TT 16
#define LL 4
#define FFD 2048
#define NHD 8
#define HDD 64
#define LDP 520   // padded LDS pitch (bf16 elems): 1040B rows -> 2-way-free b128 reads
#define SCALE_EMB 22.627416997969522f
#define GRID_MEGA 128
#define NSUB 8
#define SUBSZ 16   // GRID_MEGA / NSUB

typedef __attribute__((ext_vector_type(8))) short bf16x8;   // 8 bf16 in 4 VGPRs
typedef __attribute__((ext_vector_type(4))) float f32x4;
typedef unsigned long long ull;

__device__ __forceinline__ f32x4 mfma16(bf16x8 a, bf16x8 b, f32x4 c){
  return __builtin_amdgcn_mfma_f32_16x16x32_bf16(a, b, c, 0, 0, 0);
}

// ---------------- helpers ----------------
__device__ __forceinline__ float wave_sum(float v){
  for (int o = 32; o; o >>= 1) v += __shfl_down(v, o);
  return __shfl(v, 0);
}
__device__ __forceinline__ unsigned short f_to_bf(float f){
  unsigned u = __float_as_uint(f);
  unsigned r = (u + 0x7fffu + ((u >> 16) & 1u)) >> 16;
  return (unsigned short)r;
}
__device__ __forceinline__ float2 bf2_to_f2(const unsigned short* p){
  unsigned u = *(const unsigned*)p;
  float2 r;
  r.x = __uint_as_float(u << 16);
  r.y = __uint_as_float(u & 0xffff0000u);
  return r;
}

// ---- coherent (cross-XCD) access primitives: sc0/sc1 via agent-scope atomics.
// These bypass the non-coherent per-XCD L2 so NO bulk cache fences are needed
// at barriers; normally-cached weight lines stay L2-resident across all phases.
union UF { ull u; float f[2]; unsigned short s[4]; };
__device__ __forceinline__ ull ld_cv(const void* p){
  return __hip_atomic_load((const ull*)p, __ATOMIC_RELAXED, __HIP_MEMORY_SCOPE_AGENT);
}
__device__ __forceinline__ void st_cv(void* p, ull v){
  __hip_atomic_store((ull*)p, v, __ATOMIC_RELAXED, __HIP_MEMORY_SCOPE_AGENT);
}
__device__ __forceinline__ void upk2(ull u, float* f){ UF x; x.u = u; f[0] = x.f[0]; f[1] = x.f[1]; }
__device__ __forceinline__ ull pk2(float a, float b){ UF x; x.f[0] = a; x.f[1] = b; return x.u; }
__device__ __forceinline__ ull pkbf4(float a, float b, float c, float d){
  UF x; x.s[0] = f_to_bf(a); x.s[1] = f_to_bf(b); x.s[2] = f_to_bf(c); x.s[3] = f_to_bf(d); return x.u;
}

// 2-level grid barrier, NO cache fences. bar[0]=root, bar[16+i*16]=sub i (64B apart).
// Ordering: __syncthreads drains each wave's vmcnt (sc1 stores are then at the
// coherence point); consumers use sc1 loads so no invalidate is needed.
__device__ __forceinline__ void gsync(unsigned* bar, unsigned& gen){
  gen++;
  asm volatile("s_waitcnt vmcnt(0)" ::: "memory");
  __syncthreads();
  if (threadIdx.x == 0){
    unsigned* sub = bar + 16 + (blockIdx.x & (NSUB-1))*16;
    unsigned old = __hip_atomic_fetch_add(sub, 1u, __ATOMIC_RELAXED, __HIP_MEMORY_SCOPE_AGENT);
    if (old == gen*(unsigned)SUBSZ - 1u)
      __hip_atomic_fetch_add(bar, 1u, __ATOMIC_RELAXED, __HIP_MEMORY_SCOPE_AGENT);
    while (__hip_atomic_load(bar, __ATOMIC_RELAXED, __HIP_MEMORY_SCOPE_AGENT) < gen*(unsigned)NSUB)
      __builtin_amdgcn_s_sleep(1);
  }
  __syncthreads();
  asm volatile("" ::: "memory");
}

// fp32 VALU GEMM core (kept for the one-off prologue kernels k_penc/k_pca)
__device__ __forceinline__ void gemm_chunk(const float* __restrict__ wrow0, int ldw,
    const unsigned short* xs, float* wt, float acc[4][2]){
  const int t = threadIdx.x, fg = t & 15, bg = t >> 4;
  #pragma unroll 1
  for (int c = 0; c < 8; ++c){
    const int k0 = c*64;
    __syncthreads();
    {
      int i = t*4;
      #pragma unroll
      for (int p = 0; p < 4; ++p, i += 1024){
        const int fr = i >> 6, kk = i & 63;
        float4 v = *(const float4*)(wrow0 + (size_t)fr*ldw + k0 + kk);
        wt[(kk+0)*68 + fr] = v.x;
        wt[(kk+1)*68 + fr] = v.y;
        wt[(kk+2)*68 + fr] = v.z;
        wt[(kk+3)*68 + fr] = v.w;
      }
    }
    __syncthreads();
    const unsigned short* xr0 = xs + (bg*2)*EE + k0;
    const unsigned short* xr1 = xr0 + EE;
    #pragma unroll 8
    for (int k = 0; k < 64; k += 2){
      float w0[4], w1[4];
      *(float4*)w0 = *(const float4*)(wt + (k+0)*68 + fg*4);
      *(float4*)w1 = *(const float4*)(wt + (k+1)*68 + fg*4);
      float2 xv0 = bf2_to_f2(xr0 + k);
      float2 xv1 = bf2_to_f2(xr1 + k);
      #pragma unroll
      for (int i = 0; i < 4; ++i){
        acc[i][0] += w0[i]*xv0.x + w1[i]*xv0.y;
        acc[i][1] += w0[i]*xv1.x + w1[i]*xv1.y;
      }
    }
  }
}

// Stage [B,E] activations into padded-LDS bf16 via COHERENT loads.
// use_ln: apply pending LN (gamma g, beta bt) to ybuf rows; optionally also
// write the LN'd fp32 rows to xlnout (coherent stores).
__device__ __forceinline__ void stage_x_cv(unsigned short* xs,
    const float* __restrict__ xsrc, const float* __restrict__ ybuf,
    const float* __restrict__ g, const float* __restrict__ bt, int use_ln,
    float* __restrict__ xlnout){
  if (!use_ln){
    for (int i = threadIdx.x*4; i < BB*EE; i += 1024){
      ull u0 = ld_cv(xsrc + i);
      ull u1 = ld_cv(xsrc + i + 2);
      int r = i >> 9, c = i & 511;
      float f0[2], f1[2]; upk2(u0, f0); upk2(u1, f1);
      *(ull*)(xs + r*LDP + c) = pkbf4(f0[0], f0[1], f1[0], f1[1]);
    }
  } else {
    const int lane = threadIdx.x & 63, wv = threadIdx.x >> 6;
    const int c0 = lane*4, c1 = 256 + lane*4;
    const float g0a = g[c0], g0b = g[c0+1], g0c = g[c0+2], g0d = g[c0+3];
    const float g1a = g[c1], g1b = g[c1+1], g1c = g[c1+2], g1d = g[c1+3];
    const float b0a = bt[c0], b0b = bt[c0+1], b0c = bt[c0+2], b0d = bt[c0+3];
    const float b1a = bt[c1], b1b = bt[c1+1], b1c = bt[c1+2], b1d = bt[c1+3];
    const float* yr = ybuf + (size_t)(wv*8)*EE;
    ull a0 = ld_cv(yr + c0), a1 = ld_cv(yr + c0 + 2);
    ull a2 = ld_cv(yr + c1), a3 = ld_cv(yr + c1 + 2);
    for (int r = wv*8; r < wv*8 + 8; ++r){
      ull n0 = 0, n1 = 0, n2 = 0, n3 = 0;
      if (r < wv*8 + 7){
        const float* yn = ybuf + (size_t)(r+1)*EE;
        n0 = ld_cv(yn + c0); n1 = ld_cv(yn + c0 + 2);
        n2 = ld_cv(yn + c1); n3 = ld_cv(yn + c1 + 2);
      }
      float v[8];
      upk2(a0, v+0); upk2(a1, v+2); upk2(a2, v+4); upk2(a3, v+6);
      float s = 0.f, s2 = 0.f;
      #pragma unroll
      for (int j = 0; j < 8; ++j){ s += v[j]; s2 += v[j]*v[j]; }
      s = wave_sum(s); s2 = wave_sum(s2);
      float m = s * (1.f/EE);
      float inv = rsqrtf(s2*(1.f/EE) - m*m + 1e-5f);
      float o0 = (v[0]-m)*inv*g0a + b0a, o1 = (v[1]-m)*inv*g0b + b0b;
      float o2v = (v[2]-m)*inv*g0c + b0c, o3 = (v[3]-m)*inv*g0d + b0d;
      float o4 = (v[4]-m)*inv*g1a + b1a, o5 = (v[5]-m)*inv*g1b + b1b;
      float o6 = (v[6]-m)*inv*g1c + b1c, o7 = (v[7]-m)*inv*g1d + b1d;
      *(ull*)(xs + r*LDP + c0) = pkbf4(o0, o1, o2v, o3);
      *(ull*)(xs + r*LDP + c1) = pkbf4(o4, o5, o6, o7);
      if (xlnout){
        st_cv(xlnout + (size_t)r*EE + c0,     pk2(o0, o1));
        st_cv(xlnout + (size_t)r*EE + c0 + 2, pk2(o2v, o3));
        st_cv(xlnout + (size_t)r*EE + c1,     pk2(o4, o5));
        st_cv(xlnout + (size_t)r*EE + c1 + 2, pk2(o6, o7));
      }
      a0 = n0; a1 = n1; a2 = n2; a3 = n3;
    }
  }
  __syncthreads();
}

// Stage a 32x512 bf16 panel (row stride srcld) into xs via coherent loads.
__device__ __forceinline__ void stage_bf_panel(unsigned short* xs,
    const unsigned short* __restrict__ src, int srcld){
  for (int i = threadIdx.x*16; i < BB*512; i += 4096){
    int r = i >> 9, c = i & 511;
    const unsigned short* s = src + (size_t)r*srcld + c;
    ull u0 = ld_cv(s), u1 = ld_cv(s+4), u2 = ld_cv(s+8), u3 = ld_cv(s+12);
    ull* dst = (ull*)(xs + r*LDP + c);
    dst[0] = u0; dst[1] = u1; dst[2] = u2; dst[3] = u3;
  }
  __syncthreads();
}

// ---------------- prologue kernels ----------------

__global__ __launch_bounds__(256) void k_init(const float* __restrict__ special,
    float* __restrict__ dseq, float* __restrict__ x, unsigned* __restrict__ bar){
  if (blockIdx.x == 0) bar[threadIdx.x] = 0u;
  int idx = blockIdx.x*256 + threadIdx.x;
  if (idx < BB*VV){
    int b = idx >> 13, v = idx & (VV-1);
    dseq[(size_t)b*((TT+1)*VV) + (size_t)TT*VV + v] = (v == 0) ? 1.f : 0.f;
  } else {
    int i = idx - BB*VV;
    x[i] = special[i & (EE-1)];
  }
}

__global__ __launch_bounds__(256) void k_penc(const float* __restrict__ enc,
    const float* __restrict__ w, const float* __restrict__ bias, float* __restrict__ venc){
  __shared__ unsigned short xs[BB*EE];
  __shared__ float wt[64*68];
  const int l = blockIdx.x >> 3, et = blockIdx.x & 7;
  for (int i = threadIdx.x; i < BB*EE; i += 256) xs[i] = f_to_bf(enc[i]);
  const int t = threadIdx.x, fg = t & 15, bg = t >> 4;
  const int f0 = et*64;
  const float* wl = w + (size_t)l*3*EE*EE + (size_t)(2*EE + f0)*EE;
  const float* bl = bias + l*3*EE + 2*EE + f0;
  float acc[4][2];
  #pragma unroll
  for (int i = 0; i < 4; ++i){ float bv = bl[fg*4+i]; acc[i][0] = bv; acc[i][1] = bv; }
  gemm_chunk(wl, EE, xs, wt, acc);
  #pragma unroll
  for (int i = 0; i < 4; ++i)
    #pragma unroll
    for (int j = 0; j < 2; ++j)
      venc[(size_t)l*BB*EE + (bg*2+j)*EE + f0 + fg*4 + i] = acc[i][j];
}

__global__ __launch_bounds__(256) void k_pca(const float* __restrict__ venc,
    const float* __restrict__ w, const float* __restrict__ bias, float* __restrict__ cac){
  __shared__ unsigned short xs[BB*EE];
  __shared__ float wt[64*68];
  const int l = blockIdx.x >> 3, et = blockIdx.x & 7;
  const float* vin = venc + (size_t)l*BB*EE;
  for (int i = threadIdx.x; i < BB*EE; i += 256) xs[i] = f_to_bf(vin[i]);
  const int t = threadIdx.x, fg = t & 15, bg = t >> 4;
  const int f0 = et*64;
  const float* wl = w + (size_t)l*EE*EE + (size_t)f0*EE;
  const float* bl = bias + l*EE + f0;
  float acc[4][2];
  #pragma unroll
  for (int i = 0; i < 4; ++i){ float bv = bl[fg*4+i]; acc[i][0] = bv; acc[i][1] = bv; }
  gemm_chunk(wl, EE, xs, wt, acc);
  #pragma unroll
  for (int i = 0; i < 4; ++i)
    #pragma unroll
    for (int j = 0; j < 2; ++j)
      cac[(size_t)l*BB*EE + (bg*2+j)*EE + f0 + fg*4 + i] = acc[i][j];
}

__global__ __launch_bounds__(256) void k_cvt(const float* __restrict__ s,
    unsigned short* __restrict__ d, int n4){
  int i = blockIdx.x*256 + threadIdx.x;
  if (i < n4){
    float4 v = ((const float4*)s)[i];
    ushort4 o;
    o.x = f_to_bf(v.x); o.y = f_to_bf(v.y); o.z = f_to_bf(v.z); o.w = f_to_bf(v.w);
    ((ushort4*)d)[i] = o;
  }
}

__global__ __launch_bounds__(256) void k_embT(const float* __restrict__ emb,
    unsigned short* __restrict__ eT){
  __shared__ unsigned short tl[64][68];
  const int vt = blockIdx.x >> 3, et = blockIdx.x & 7;
  const int v0 = vt*64, e0 = et*64;
  for (int i = threadIdx.x; i < 64*64; i += 256){
    int vv = i >> 6, ee = i & 63;
    tl[vv][ee] = f_to_bf(emb[(size_t)(v0+vv)*EE + e0 + ee]);
  }
  __syncthreads();
  for (int i = threadIdx.x; i < 64*64; i += 256){
    int ee = i >> 6, vv = i & 63;
    eT[(size_t)(e0+ee)*VV + v0 + vv] = tl[vv][ee];
  }
}

// ---------------- mega-kernel phases ----------------

__device__ void ph_qkv_attn(int h, unsigned short* xs, float* qs, float* att,
    const float* __restrict__ x, const float* __restrict__ ybuf,
    const float* __restrict__ lg, const float* __restrict__ lb, int use_ln,
    const unsigned short* __restrict__ Wb, const float* __restrict__ bias,
    float* __restrict__ kcl, float* __restrict__ vcl, float* __restrict__ xln,
    unsigned short* __restrict__ obf, int tpos, int tlen){
  stage_x_cv(xs, x, ybuf, lg, lb, use_ln, (use_ln && h == 0) ? xln : nullptr);
  const int t = threadIdx.x, w = t >> 6, lane = t & 63;
  const int lm = lane & 15, kg = lane >> 4;
  const unsigned short* b0r = xs + lm*LDP + kg*8;
  const unsigned short* b1r = xs + (lm+16)*LDP + kg*8;
  #pragma unroll
  for (int c = 0; c < 3; ++c){
    const int fbase = c*EE + h*64 + w*16;
    const unsigned short* ar = Wb + (size_t)(fbase + lm)*EE + kg*8;
    f32x4 acc0 = {0.f,0.f,0.f,0.f}, acc1 = {0.f,0.f,0.f,0.f};
    #pragma unroll 4
    for (int ks = 0; ks < 16; ++ks){
      bf16x8 a  = *reinterpret_cast<const bf16x8*>(ar + ks*32);
      bf16x8 b0 = *reinterpret_cast<const bf16x8*>(b0r + ks*32);
      bf16x8 b1 = *reinterpret_cast<const bf16x8*>(b1r + ks*32);
      acc0 = mfma16(a, b0, acc0);
      acc1 = mfma16(a, b1, acc1);
    }
    #pragma unroll
    for (int r = 0; r < 4; ++r){
      const int frel = w*16 + kg*4 + r;                 // 0..63 within chunk
      const float bv = bias[c*EE + h*64 + frel];
      float v0 = acc0[r] + bv, v1 = acc1[r] + bv;
      if (c == 0){
        qs[lm*68 + frel] = v0;
        qs[(lm+16)*68 + frel] = v1;
      } else if (c == 1){
        // same-block producer/consumer: normal cached stores are safe
        kcl[((lm*NHD + h)*TT + tpos)*HDD + frel] = v0;
        kcl[(((lm+16)*NHD + h)*TT + tpos)*HDD + frel] = v1;
      } else {
        vcl[((lm*NHD + h)*TT + tpos)*HDD + frel] = v0;
        vcl[(((lm+16)*NHD + h)*TT + tpos)*HDD + frel] = v1;
      }
    }
  }
  __syncthreads();
  // scores: 2 (b,j) pairs per thread
  #pragma unroll
  for (int pp = 0; pp < 2; ++pp){
    const int p = t + pp*256;
    const int b = p >> 4, j = p & 15;
    if (j < tlen){
      const float* qrow = qs + b*68;
      const float* krow = kcl + ((b*NHD + h)*TT + j)*HDD;
      float a = 0.f;
      #pragma unroll
      for (int d = 0; d < HDD; d += 4){
        float4 qv = *(const float4*)(qrow + d);
        float4 kv = *(const float4*)(krow + d);
        a += qv.x*kv.x + qv.y*kv.y + qv.z*kv.z + qv.w*kv.w;
      }
      att[b*16 + j] = a*0.125f;
    }
  }
  __syncthreads();
  if (t < 32){
    const int b = t;
    float m = -1e30f;
    for (int j = 0; j < tlen; ++j) m = fmaxf(m, att[b*16 + j]);
    float s = 0.f;
    for (int j = 0; j < tlen; ++j) s += __expf(att[b*16 + j] - m);
    float inv = 1.f/s;
    for (int j = 0; j < tlen; ++j) att[b*16 + j] = __expf(att[b*16 + j] - m)*inv;
  }
  __syncthreads();
  // PV: thread -> (b, 8 d-values); obf is cross-block -> coherent stores
  {
    const int b = t >> 3, d0 = (t & 7)*8;
    float acc[8];
    #pragma unroll
    for (int i = 0; i < 8; ++i) acc[i] = 0.f;
    const float* vrow = vcl + ((b*NHD + h)*TT)*HDD + d0;
    for (int j = 0; j < tlen; ++j){
      const float a = att[b*16 + j];
      float4 v0 = *(const float4*)(vrow + j*HDD);
      float4 v1 = *(const float4*)(vrow + j*HDD + 4);
      acc[0] += a*v0.x; acc[1] += a*v0.y; acc[2] += a*v0.z; acc[3] += a*v0.w;
      acc[4] += a*v1.x; acc[5] += a*v1.y; acc[6] += a*v1.z; acc[7] += a*v1.w;
    }
    st_cv(obf + b*EE + h*HDD + d0,     pkbf4(acc[0], acc[1], acc[2], acc[3]));
    st_cv(obf + b*EE + h*HDD + d0 + 4, pkbf4(acc[4], acc[5], acc[6], acc[7]));
  }
}

__device__ void ph_outp(int blk, unsigned short* xs, const unsigned short* __restrict__ obf,
    const unsigned short* __restrict__ Wb, const float* __restrict__ ob,
    const float* __restrict__ resid, float* __restrict__ o2){
  stage_bf_panel(xs, obf, EE);
  const int t = threadIdx.x, w = t >> 6, l = t & 63;
  const int lm = l & 15, kg = l >> 4;
  const int f0w = blk*64 + w*16;
  const unsigned short* ar = Wb + (size_t)(f0w + lm)*EE + kg*8;
  const unsigned short* b0r = xs + lm*LDP + kg*8;
  const unsigned short* b1r = xs + (lm+16)*LDP + kg*8;
  f32x4 acc0 = {0.f,0.f,0.f,0.f}, acc1 = {0.f,0.f,0.f,0.f};
  #pragma unroll 4
  for (int ks = 0; ks < 16; ++ks){
    bf16x8 a  = *reinterpret_cast<const bf16x8*>(ar + ks*32);
    bf16x8 b0 = *reinterpret_cast<const bf16x8*>(b0r + ks*32);
    bf16x8 b1 = *reinterpret_cast<const bf16x8*>(b1r + ks*32);
    acc0 = mfma16(a, b0, acc0);
    acc1 = mfma16(a, b1, acc1);
  }
  const int fb = f0w + kg*4;
  float r0[4], r1[4];
  upk2(ld_cv(resid + lm*EE + fb), r0); upk2(ld_cv(resid + lm*EE + fb + 2), r0+2);
  upk2(ld_cv(resid + (lm+16)*EE + fb), r1); upk2(ld_cv(resid + (lm+16)*EE + fb + 2), r1+2);
  const float b0v = ob[fb], b1v = ob[fb+1], b2v = ob[fb+2], b3v = ob[fb+3];
  st_cv(o2 + lm*EE + fb,     pk2(acc0[0]+b0v+r0[0], acc0[1]+b1v+r0[1]));
  st_cv(o2 + lm*EE + fb + 2, pk2(acc0[2]+b2v+r0[2], acc0[3]+b3v+r0[3]));
  st_cv(o2 + (lm+16)*EE + fb,     pk2(acc1[0]+b0v+r1[0], acc1[1]+b1v+r1[1]));
  st_cv(o2 + (lm+16)*EE + fb + 2, pk2(acc1[2]+b2v+r1[2], acc1[3]+b3v+r1[3]));
}

__device__ void ph_ffn1(int blk, unsigned short* xs,
    const float* __restrict__ o2, const float* __restrict__ cac,
    const float* __restrict__ g1, const float* __restrict__ b1g,
    const float* __restrict__ g2, const float* __restrict__ b2g,
    const float* __restrict__ b2bias,
    const unsigned short* __restrict__ Wb, const float* __restrict__ bias,
    unsigned short* __restrict__ Hb, float* __restrict__ ybuf){
  {
    float* yi = (blk == 0) ? ybuf : nullptr;
    const int lane = threadIdx.x & 63, wv = threadIdx.x >> 6;
    const int c0 = lane*4, c1 = 256 + lane*4;
    for (int r = wv*8; r < wv*8 + 8; ++r){
      const float* orow = o2 + (size_t)r*EE;
      float v[8];
      upk2(ld_cv(orow + c0), v+0); upk2(ld_cv(orow + c0 + 2), v+2);
      upk2(ld_cv(orow + c1), v+4); upk2(ld_cv(orow + c1 + 2), v+6);
      float s = 0.f, s2 = 0.f;
      #pragma unroll
      for (int j = 0; j < 8; ++j){ s += v[j]; s2 += v[j]*v[j]; }
      s = wave_sum(s); s2 = wave_sum(s2);
      float m = s*(1.f/EE), inv = rsqrtf(s2*(1.f/EE) - m*m + 1e-5f);
      float4 ca0 = *(const float4*)(cac + (size_t)r*EE + c0);
      float4 ca1 = *(const float4*)(cac + (size_t)r*EE + c1);
      float nv[8]; float u = 0.f, u2 = 0.f;
      nv[0] = (v[0]-m)*inv*g1[c0+0] + b1g[c0+0] + ca0.x;
      nv[1] = (v[1]-m)*inv*g1[c0+1] + b1g[c0+1] + ca0.y;
      nv[2] = (v[2]-m)*inv*g1[c0+2] + b1g[c0+2] + ca0.z;
      nv[3] = (v[3]-m)*inv*g1[c0+3] + b1g[c0+3] + ca0.w;
      nv[4] = (v[4]-m)*inv*g1[c1+0] + b1g[c1+0] + ca1.x;
      nv[5] = (v[5]-m)*inv*g1[c1+1] + b1g[c1+1] + ca1.y;
      nv[6] = (v[6]-m)*inv*g1[c1+2] + b1g[c1+2] + ca1.z;
      nv[7] = (v[7]-m)*inv*g1[c1+3] + b1g[c1+3] + ca1.w;
      #pragma unroll
      for (int j = 0; j < 8; ++j){ u += nv[j]; u2 += nv[j]*nv[j]; }
      u = wave_sum(u); u2 = wave_sum(u2);
      float m2 = u*(1.f/EE), inv2 = rsqrtf(u2*(1.f/EE) - m2*m2 + 1e-5f);
      float o0 = (nv[0]-m2)*inv2*g2[c0+0] + b2g[c0+0];
      float o1 = (nv[1]-m2)*inv2*g2[c0+1] + b2g[c0+1];
      float o2v = (nv[2]-m2)*inv2*g2[c0+2] + b2g[c0+2];
      float o3 = (nv[3]-m2)*inv2*g2[c0+3] + b2g[c0+3];
      float o4 = (nv[4]-m2)*inv2*g2[c1+0] + b2g[c1+0];
      float o5 = (nv[5]-m2)*inv2*g2[c1+1] + b2g[c1+1];
      float o6 = (nv[6]-m2)*inv2*g2[c1+2] + b2g[c1+2];
      float o7 = (nv[7]-m2)*inv2*g2[c1+3] + b2g[c1+3];
      *(ull*)(xs + r*LDP + c0) = pkbf4(o0, o1, o2v, o3);
      *(ull*)(xs + r*LDP + c1) = pkbf4(o4, o5, o6, o7);
      if (yi){
        st_cv(yi + (size_t)r*EE + c0,     pk2(o0 + b2bias[c0+0], o1 + b2bias[c0+1]));
        st_cv(yi + (size_t)r*EE + c0 + 2, pk2(o2v + b2bias[c0+2], o3 + b2bias[c0+3]));
        st_cv(yi + (size_t)r*EE + c1,     pk2(o4 + b2bias[c1+0], o5 + b2bias[c1+1]));
        st_cv(yi + (size_t)r*EE + c1 + 2, pk2(o6 + b2bias[c1+2], o7 + b2bias[c1+3]));
      }
    }
    __syncthreads();
  }
  const int t = threadIdx.x, w = t >> 6, l = t & 63;
  const int lm = l & 15, kg = l >> 4;
  const int f0w = blk*64 + w*16;
  const unsigned short* ar = Wb + (size_t)(f0w + lm)*EE + kg*8;
  const unsigned short* b0r = xs + lm*LDP + kg*8;
  const unsigned short* b1r = xs + (lm+16)*LDP + kg*8;
  f32x4 acc0 = {0.f,0.f,0.f,0.f}, acc1 = {0.f,0.f,0.f,0.f};
  #pragma unroll 4
  for (int ks = 0; ks < 16; ++ks){
    bf16x8 a  = *reinterpret_cast<const bf16x8*>(ar + ks*32);
    bf16x8 b0 = *reinterpret_cast<const bf16x8*>(b0r + ks*32);
    bf16x8 b1 = *reinterpret_cast<const bf16x8*>(b1r + ks*32);
    acc0 = mfma16(a, b0, acc0);
    acc1 = mfma16(a, b1, acc1);
  }
  const int fb = f0w + kg*4;
  float h0[4], h1[4];
  #pragma unroll
  for (int r = 0; r < 4; ++r){
    const float bv = bias[fb + r];
    float v0 = acc0[r] + bv, v1 = acc1[r] + bv;
    h0[r] = 0.5f*v0*(1.f + erff(v0*0.70710678118654752f));
    h1[r] = 0.5f*v1*(1.f + erff(v1*0.70710678118654752f));
  }
  st_cv(Hb + lm*FFD + fb,      pkbf4(h0[0], h0[1], h0[2], h0[3]));
  st_cv(Hb + (lm+16)*FFD + fb, pkbf4(h1[0], h1[1], h1[2], h1[3]));
}

__device__ void ph_ffn2(int blk, unsigned short* xs, const unsigned short* __restrict__ Hb,
    const unsigned short* __restrict__ Wb, float* __restrict__ ybuf){
  const int k0 = (blk >> 3)*512;
  stage_bf_panel(xs, Hb + k0, FFD);
  const int t = threadIdx.x, w = t >> 6, l = t & 63;
  const int lm = l & 15, kg = l >> 4;
  const int f0w = (blk & 7)*64 + w*16;
  const unsigned short* ar = Wb + (size_t)(f0w + lm)*FFD + k0 + kg*8;
  const unsigned short* b0r = xs + lm*LDP + kg*8;
  const unsigned short* b1r = xs + (lm+16)*LDP + kg*8;
  f32x4 acc0 = {0.f,0.f,0.f,0.f}, acc1 = {0.f,0.f,0.f,0.f};
  #pragma unroll 4
  for (int ks = 0; ks < 16; ++ks){
    bf16x8 a  = *reinterpret_cast<const bf16x8*>(ar + ks*32);
    bf16x8 b0 = *reinterpret_cast<const bf16x8*>(b0r + ks*32);
    bf16x8 b1 = *reinterpret_cast<const bf16x8*>(b1r + ks*32);
    acc0 = mfma16(a, b0, acc0);
    acc1 = mfma16(a, b1, acc1);
  }
  #pragma unroll
  for (int r = 0; r < 4; ++r){
    const int f = f0w + kg*4 + r;
    atomicAdd(&ybuf[lm*EE + f], acc0[r]);      // device-scope, coherent (m20)
    atomicAdd(&ybuf[(lm+16)*EE + f], acc1[r]);
  }
}

__device__ void ph_logits(int blk, unsigned short* xs,
    const float* __restrict__ ybuf, const float* __restrict__ lng, const float* __restrict__ lnb,
    const unsigned short* __restrict__ Wb, const float* __restrict__ bias,
    float* __restrict__ logits){
  stage_x_cv(xs, nullptr, ybuf, lng, lnb, 1, nullptr);
  const int t = threadIdx.x, w = t >> 6, l = t & 63;
  const int lm = l & 15, kg = l >> 4;
  const int f0w = blk*64 + w*16;
  const unsigned short* ar = Wb + (size_t)(f0w + lm)*EE + kg*8;
  const unsigned short* b0r = xs + lm*LDP + kg*8;
  const unsigned short* b1r = xs + (lm+16)*LDP + kg*8;
  f32x4 acc0 = {0.f,0.f,0.f,0.f}, acc1 = {0.f,0.f,0.f,0.f};
  #pragma unroll 4
  for (int ks = 0; ks < 16; ++ks){
    bf16x8 a  = *reinterpret_cast<const bf16x8*>(ar + ks*32);
    bf16x8 b0 = *reinterpret_cast<const bf16x8*>(b0r + ks*32);
    bf16x8 b1 = *reinterpret_cast<const bf16x8*>(b1r + ks*32);
    acc0 = mfma16(a, b0, acc0);
    acc1 = mfma16(a, b1, acc1);
  }
  const int fb = f0w + kg*4;
  const float b0v = bias[fb], b1v = bias[fb+1], b2v = bias[fb+2], b3v = bias[fb+3];
  st_cv(logits + (size_t)lm*VV + fb,     pk2(acc0[0]+b0v, acc0[1]+b1v));
  st_cv(logits + (size_t)lm*VV + fb + 2, pk2(acc0[2]+b2v, acc0[3]+b3v));
  st_cv(logits + (size_t)(lm+16)*VV + fb,     pk2(acc1[0]+b0v, acc1[1]+b1v));
  st_cv(logits + (size_t)(lm+16)*VV + fb + 2, pk2(acc1[2]+b2v, acc1[3]+b3v));
}

__device__ void ph_softmax(int b, float* red, const float* __restrict__ logits,
    const float* __restrict__ gum, float* __restrict__ dseq, float* __restrict__ ddist,
    unsigned short* __restrict__ sbf, float* __restrict__ x, int step){
  const int t = threadIdx.x, lane = t & 63, wv = t >> 6;
  const float* lr = logits + (size_t)b*VV;
  const float* gr = gum + (size_t)b*VV;
  float lv[32];
  #pragma unroll
  for (int g8 = 0; g8 < 8; ++g8){
    const int i0 = t*4 + g8*1024;
    upk2(ld_cv(lr + i0),     lv + g8*4);
    upk2(ld_cv(lr + i0 + 2), lv + g8*4 + 2);
  }
  float m1 = -1e30f, m2 = -1e30f;
  #pragma unroll
  for (int g8 = 0; g8 < 8; ++g8){
    const int i0 = t*4 + g8*1024;
    float4 gv = *(const float4*)(gr + i0);
    m1 = fmaxf(m1, fmaxf(fmaxf(lv[g8*4], lv[g8*4+1]), fmaxf(lv[g8*4+2], lv[g8*4+3])));
    m2 = fmaxf(m2, fmaxf(fmaxf(lv[g8*4]+gv.x, lv[g8*4+1]+gv.y),
                         fmaxf(lv[g8*4+2]+gv.z, lv[g8*4+3]+gv.w)));
  }
  for (int o = 32; o; o >>= 1){ m1 = fmaxf(m1, __shfl_down(m1,o)); m2 = fmaxf(m2, __shfl_down(m2,o)); }
  if (lane == 0){ red[wv] = m1; red[4+wv] = m2; }
  __syncthreads();
  m1 = fmaxf(fmaxf(red[0],red[1]), fmaxf(red[2],red[3]));
  m2 = fmaxf(fmaxf(red[4],red[5]), fmaxf(red[6],red[7]));
  __syncthreads();
  float s1 = 0.f, s2 = 0.f;
  #pragma unroll
  for (int g8 = 0; g8 < 8; ++g8){
    const int i0 = t*4 + g8*1024;
    float4 gv = *(const float4*)(gr + i0);
    s1 += __expf(lv[g8*4]-m1) + __expf(lv[g8*4+1]-m1) + __expf(lv[g8*4+2]-m1) + __expf(lv[g8*4+3]-m1);
    s2 += __expf(lv[g8*4]+gv.x-m2) + __expf(lv[g8*4+1]+gv.y-m2)
        + __expf(lv[g8*4+2]+gv.z-m2) + __expf(lv[g8*4+3]+gv.w-m2);
  }
  for (int o = 32; o; o >>= 1){ s1 += __shfl_down(s1,o); s2 += __shfl_down(s2,o); }
  if (lane == 0){ red[wv] = s1; red[4+wv] = s2; }
  __syncthreads();
  s1 = red[0]+red[1]+red[2]+red[3];
  s2 = red[4]+red[5]+red[6]+red[7];
  float r1 = 1.f/s1, r2 = 1.f/s2;
  float* dq = dseq + (size_t)b*((TT+1)*VV) + (size_t)step*VV;
  float* dd = ddist + (size_t)b*VV;
  #pragma unroll
  for (int g8 = 0; g8 < 8; ++g8){
    const int i0 = t*4 + g8*1024;
    float4 gv = *(const float4*)(gr + i0);
    float4 ddv, dqv;
    ddv.x = __expf(lv[g8*4]-m1)*r1;   ddv.y = __expf(lv[g8*4+1]-m1)*r1;
    ddv.z = __expf(lv[g8*4+2]-m1)*r1; ddv.w = __expf(lv[g8*4+3]-m1)*r1;
    dqv.x = __expf(lv[g8*4]+gv.x-m2)*r2;   dqv.y = __expf(lv[g8*4+1]+gv.y-m2)*r2;
    dqv.z = __expf(lv[g8*4+2]+gv.z-m2)*r2; dqv.w = __expf(lv[g8*4+3]+gv.w-m2)*r2;
    *(float4*)(dd + i0) = ddv;   // output buffer: host-consumed, normal stores
    *(float4*)(dq + i0) = dqv;
    st_cv(sbf + (size_t)b*VV + i0, pkbf4(dqv.x, dqv.y, dqv.z, dqv.w));
  }
  st_cv(x + (size_t)b*EE + t*2, 0ull);
}

__device__ void ph_embed(int blk, unsigned short* xs, const unsigned short* __restrict__ eT,
    const unsigned short* __restrict__ sbf, float* __restrict__ x){
  const int v0 = (blk >> 3)*512;
  stage_bf_panel(xs, sbf + v0, VV);
  const int t = threadIdx.x, w = t >> 6, l = t & 63;
  const int lm = l & 15, kg = l >> 4;
  const int e0w = (blk & 7)*64 + w*16;
  const unsigned short* ar  = eT + (size_t)(e0w + lm)*VV + v0 + kg*8;
  const unsigned short* b0r = xs + lm*LDP + kg*8;
  const unsigned short* b1r = xs + (lm+16)*LDP + kg*8;
  f32x4 acc0 = {0.f,0.f,0.f,0.f}, acc1 = {0.f,0.f,0.f,0.f};
  #pragma unroll 4
  for (int ks = 0; ks < 16; ++ks){
    bf16x8 a  = *reinterpret_cast<const bf16x8*>(ar + ks*32);
    bf16x8 b0 = *reinterpret_cast<const bf16x8*>(b0r + ks*32);
    bf16x8 b1 = *reinterpret_cast<const bf16x8*>(b1r + ks*32);
    acc0 = mfma16(a, b0, acc0);
    acc1 = mfma16(a, b1, acc1);
  }
  #pragma unroll
  for (int r = 0; r < 4; ++r){
    const int e = e0w + kg*4 + r;
    atomicAdd(&x[lm*EE + e], acc0[r]*SCALE_EMB);
    atomicAdd(&x[(lm+16)*EE + e], acc1[r]*SCALE_EMB);
  }
}

// ---------------- the megakernel ----------------

struct MegaParams {
  float* x; float* y; float* xln; float* o2; float* logits;
  const float* cac;
  float* kcache; float* vcache;
  unsigned short* obf; unsigned short* Hb; unsigned short* sbf;
  const unsigned short* wqkvb; const unsigned short* owb;
  const unsigned short* w1b; const unsigned short* w2b;
  const unsigned short* outwb; const unsigned short* eTb;
  const float* saqb; const float* saob;
  const float* l1g; const float* l1b; const float* l2g; const float* l2b;
  const float* l3g; const float* l3b;
  const float* b1; const float* b2; const float* outb; const float* gumb;
  float* dseq; float* ddist;
  unsigned* bar;
};

__global__ __launch_bounds__(256) void k_mega(MegaParams P){
  __shared__ __align__(16) unsigned char SMEM[44032];
  unsigned short* xs = (unsigned short*)SMEM;          // 33280 B  (BB*LDP bf16)
  float* qs  = (float*)(SMEM + 33280);                 //  8704 B  (32x68 f32)
  float* att = (float*)(SMEM + 41984);                 //  2048 B  (32x16 f32)
  const int blk = blockIdx.x;
  unsigned gen = 0;

  for (int step = 0; step < TT; ++step){
    const int tpos = step, tlen = step + 1;
    for (int l = 0; l < LL; ++l){
      const int use_ln = (l > 0);
      const float* lg = P.l3g + (use_ln ? (l-1)*EE : 0);
      const float* lb = P.l3b + (use_ln ? (l-1)*EE : 0);
      float* kcl = P.kcache + (size_t)l*BB*EE*TT;
      float* vcl = P.vcache + (size_t)l*BB*EE*TT;
      if (blk < NHD)
        ph_qkv_attn(blk, xs, qs, att, P.x, P.y, lg, lb, use_ln,
            P.wqkvb + (size_t)l*3*EE*EE, P.saqb + (size_t)l*3*EE,
            kcl, vcl, P.xln, P.obf, tpos, tlen);
      gsync(P.bar, gen);
      if (blk < 8)
        ph_outp(blk, xs, P.obf, P.owb + (size_t)l*EE*EE, P.saob + (size_t)l*EE,
            use_ln ? P.xln : P.x, P.o2);
      gsync(P.bar, gen);
      if (blk < 32)
        ph_ffn1(blk, xs, P.o2, P.cac + (size_t)l*BB*EE,
            P.l1g + l*EE, P.l1b + l*EE, P.l2g + l*EE, P.l2b + l*EE, P.b2 + l*EE,
            P.w1b + (size_t)l*FFD*EE, P.b1 + l*FFD, P.Hb, P.y);
      gsync(P.bar, gen);
      if (blk < 32)
        ph_ffn2(blk, xs, P.Hb, P.w2b + (size_t)l*EE*FFD, P.y);
      gsync(P.bar, gen);
    }
    ph_logits(blk, xs, P.y, P.l3g + 3*EE, P.l3b + 3*EE, P.outwb, P.outb, P.logits);
    gsync(P.bar, gen);
    if (blk < 32)
      ph_softmax(blk, att, P.logits, P.gumb + (size_t)step*BB*VV,
          P.dseq, P.ddist + (size_t)step*BB*VV, P.sbf, P.x, step);
    gsync(P.bar, gen);
    ph_embed(blk, xs, P.eTb, P.sbf, P.x);
    gsync(P.bar, gen);
  }
}

// ---------------- host ----------------
extern "C" void kernel_launch(void* const* d_in, const int* in_sizes, int n_in,
                              void* d_out, int out_size, void* d_ws, size_t ws_size,
                              hipStream_t stream){
  (void)in_sizes; (void)n_in; (void)out_size; (void)ws_size;
  const float* enc  = (const float*)d_in[0];
  const float* spec = (const float*)d_in[1];
  const float* embw = (const float*)d_in[2];
  const float* outw = (const float*)d_in[3];
  const float* outb = (const float*)d_in[4];
  const float* gumb = (const float*)d_in[5];
  const float* saqw = (const float*)d_in[6];
  const float* saqb = (const float*)d_in[7];
  const float* saow = (const float*)d_in[8];
  const float* saob = (const float*)d_in[9];
  const float* caqw = (const float*)d_in[10];
  const float* caqb = (const float*)d_in[11];
  const float* caow = (const float*)d_in[12];
  const float* caob = (const float*)d_in[13];
  const float* l1g  = (const float*)d_in[14];
  const float* l1b  = (const float*)d_in[15];
  const float* l2g  = (const float*)d_in[16];
  const float* l2b  = (const float*)d_in[17];
  const float* l3g  = (const float*)d_in[18];
  const float* l3b  = (const float*)d_in[19];
  const float* w1   = (const float*)d_in[20];
  const float* b1   = (const float*)d_in[21];
  const float* w2   = (const float*)d_in[22];
  const float* b2   = (const float*)d_in[23];

  float* dout = (float*)d_out;
  float* dseq = dout;
  float* ddistbase = dout + (size_t)BB*(TT+1)*VV;

  unsigned char* p = (unsigned char*)d_ws;
  auto alloc = [&](size_t bytes) -> void* {
    void* r = (void*)p; p += (bytes + 255) & ~(size_t)255; return r;
  };
  float* x      = (float*)alloc(BB*EE*4);
  float* y      = (float*)alloc(BB*EE*4);
  float* xln    = (float*)alloc(BB*EE*4);
  float* o2     = (float*)alloc(BB*EE*4);
  float* logits = (float*)alloc((size_t)BB*VV*4);
  float* venc   = (float*)alloc((size_t)LL*BB*EE*4);
  float* cac    = (float*)alloc((size_t)LL*BB*EE*4);
  float* kcache = (float*)alloc((size_t)LL*BB*EE*TT*4);
  float* vcache = (float*)alloc((size_t)LL*BB*EE*TT*4);
  unsigned short* obf   = (unsigned short*)alloc(BB*EE*2);
  unsigned short* Hb    = (unsigned short*)alloc(BB*FFD*2);
  unsigned short* sbf   = (unsigned short*)alloc((size_t)BB*VV*2);
  unsigned short* wqkvb = (unsigned short*)alloc((size_t)LL*3*EE*EE*2);
  unsigned short* owb   = (unsigned short*)alloc((size_t)LL*EE*EE*2);
  unsigned short* w1b   = (unsigned short*)alloc((size_t)LL*FFD*EE*2);
  unsigned short* w2b   = (unsigned short*)alloc((size_t)LL*FFD*EE*2);
  unsigned short* outwb = (unsigned short*)alloc((size_t)VV*EE*2);
  unsigned short* eTb   = (unsigned short*)alloc((size_t)EE*VV*2);
  unsigned* bar = (unsigned*)alloc(1024);

  // prologue: init (+barrier reset), cross-attn constants, bf16 weight conversions
  k_init<<<1088, 256, 0, stream>>>(spec, dseq, x, bar);
  k_penc<<<32, 256, 0, stream>>>(enc, caqw, caqb, venc);
  k_pca<<<32, 256, 0, stream>>>(venc, caow, caob, cac);
  k_cvt<<<(LL*3*EE*EE/4 + 255)/256, 256, 0, stream>>>(saqw, wqkvb, LL*3*EE*EE/4);
  k_cvt<<<(LL*EE*EE/4 + 255)/256, 256, 0, stream>>>(saow, owb, LL*EE*EE/4);
  k_cvt<<<(LL*FFD*EE/4 + 255)/256, 256, 0, stream>>>(w1, w1b, LL*FFD*EE/4);
  k_cvt<<<(LL*FFD*EE/4 + 255)/256, 256, 0, stream>>>(w2, w2b, LL*FFD*EE/4);
  k_cvt<<<(VV*EE/4 + 255)/256, 256, 0, stream>>>(outw, outwb, VV*EE/4);
  k_embT<<<1024, 256, 0, stream>>>(embw, eTb);

  MegaParams mp;
  mp.x = x; mp.y = y; mp.xln = xln; mp.o2 = o2; mp.logits = logits;
  mp.cac = cac; mp.kcache = kcache; mp.vcache = vcache;
  mp.obf = obf; mp.Hb = Hb; mp.sbf = sbf;
  mp.wqkvb = wqkvb; mp.owb = owb; mp.w1b = w1b; mp.w2b = w2b;
  mp.outwb = outwb; mp.eTb = eTb;
  mp.saqb = saqb; mp.saob = saob;
  mp.l1g = l1g; mp.l1b = l1b; mp.l2g = l2g; mp.l2b = l2b;
  mp.l3g = l3g; mp.l3b = l3b;
  mp.b1 = b1; mp.b2 = b2; mp.outb = outb; mp.gumb = gumb;
  mp.dseq = dseq; mp.ddist = ddistbase;
  mp.bar = bar;

  // 128 blocks x 256 threads, 44KB LDS -> all blocks co-resident on 256 CUs;
  // grid barriers (2-level, fence-free) are safe.
  k_mega<<<GRID_MEGA, 256, 0, stream>>>(mp);
}